// Round 11
// baseline (50.782 us; speedup 1.0000x reference)
//
#include <hip/hip_runtime.h>

#define SEQ 8192
#define DM 64

typedef __bf16 bfrag __attribute__((ext_vector_type(8)));   // MFMA A/B operand
typedef __bf16 b4v   __attribute__((ext_vector_type(4)));   // 8-byte bf16 pack
typedef float  f4    __attribute__((ext_vector_type(4)));   // MFMA C/D operand

union PW { int w[4]; bfrag v; };

// fold 1/sqrt(64) * log2(e) into Q so softmax uses exp2 (bare v_exp_f32)
#define QSCALE 0.1803368801111204f

#define GLOAD16(gsrc, ldst)                                                \
    __builtin_amdgcn_global_load_lds(                                      \
        (const __attribute__((address_space(1))) unsigned int*)(gsrc),     \
        (__attribute__((address_space(3))) unsigned int*)(ldst), 16, 0, 0)

__device__ inline int pack_bf16(float a, float b) {
    const __bf16 ba = (__bf16)a, bb = (__bf16)b;
    const unsigned short ua = __builtin_bit_cast(unsigned short, ba);
    const unsigned short ub = __builtin_bit_cast(unsigned short, bb);
    return (int)(((unsigned)ub << 16) | (unsigned)ua);
}

// ---------------------------------------------------------------------------
// Kernel 0: hi/lo bf16 pre-split of x (8192x64) and Wq/Wk/Wv (64x64 each).
// Memory-bound; removes all split chains from qkv_proj.
// ---------------------------------------------------------------------------
__global__ __launch_bounds__(256) void presplit(
    const float* __restrict__ x,
    const float* __restrict__ wq, const float* __restrict__ wk,
    const float* __restrict__ wv,
    __bf16* __restrict__ Xhi, __bf16* __restrict__ Xlo,
    __bf16* __restrict__ Whi, __bf16* __restrict__ Wlo)
{
    const int gid = blockIdx.x * 256 + threadIdx.x;   // 0..134143
    const int NX = SEQ * DM / 4;                      // 131072 f4 of x
    f4 v;
    if (gid < NX) v = ((const f4*)x)[gid];
    else {
        const int wi = gid - NX;                      // 0..3071
        const int m = wi >> 10, off = wi & 1023;
        const float* w = (m == 0) ? wq : (m == 1) ? wk : wv;
        v = ((const f4*)w)[off];
    }
    b4v hi, lo;
    #pragma unroll
    for (int e = 0; e < 4; ++e) {
        const __bf16 h = (__bf16)v[e];
        hi[e] = h;
        lo[e] = (__bf16)(v[e] - (float)h);
    }
    if (gid < NX) { ((b4v*)Xhi)[gid] = hi; ((b4v*)Xlo)[gid] = lo; }
    else         { ((b4v*)Whi)[gid - NX] = hi; ((b4v*)Wlo)[gid - NX] = lo; }
}

// ---------------------------------------------------------------------------
// Kernel 1 (MFMA): 2048 wave-tasks = (16-row x-tile rt, dt). 512 blocks x 4.
// Pure MFMA + pack (inputs pre-split). acc = hi*hi + lo*hi + hi*lo (~fp32).
// Store layouts byte-identical to the round-10-verified ones:
//  Qb row-major (scaled QSCALE); Ks/Vg tile-major lane-linear (see round 10).
// ---------------------------------------------------------------------------
__global__ __launch_bounds__(256) void qkv_proj(
    const __bf16* __restrict__ Xhi, const __bf16* __restrict__ Xlo,
    const __bf16* __restrict__ Whi, const __bf16* __restrict__ Wlo,
    const float* __restrict__ bq, const float* __restrict__ bk,
    const float* __restrict__ bv,
    __bf16* __restrict__ Qb, __bf16* __restrict__ Ks, __bf16* __restrict__ Vg)
{
    const int lane = threadIdx.x & 63;
    const int wid  = threadIdx.x >> 6;
    const int task = blockIdx.x * 4 + wid;      // 0..2047
    const int rt   = task >> 2;                 // 0..511
    const int dt   = task & 3;                  // 0..3
    const int rb   = rt << 4;
    const int g = lane >> 4, r = lane & 15;

    bfrag xhi[2], xlo[2];
    #pragma unroll
    for (int kh = 0; kh < 2; ++kh) {
        xhi[kh] = *(const bfrag*)(Xhi + (rb + r) * DM + kh * 32 + g * 8);
        xlo[kh] = *(const bfrag*)(Xlo + (rb + r) * DM + kh * 32 + g * 8);
    }

    // ---- Q (m=0), K (m=1): mfma(W, X) -> D[feat][x-row] ----
    #pragma unroll
    for (int m = 0; m < 2; ++m) {
        const float* bias = m ? bk : bq;
        f4 acc = {0.f, 0.f, 0.f, 0.f};
        #pragma unroll
        for (int kh = 0; kh < 2; ++kh) {
            const bfrag whi = *(const bfrag*)(Whi + m * 4096 + (dt * 16 + r) * DM + kh * 32 + g * 8);
            const bfrag wlo = *(const bfrag*)(Wlo + m * 4096 + (dt * 16 + r) * DM + kh * 32 + g * 8);
            acc = __builtin_amdgcn_mfma_f32_16x16x32_bf16(whi, xhi[kh], acc, 0, 0, 0);
            acc = __builtin_amdgcn_mfma_f32_16x16x32_bf16(wlo, xhi[kh], acc, 0, 0, 0);
            acc = __builtin_amdgcn_mfma_f32_16x16x32_bf16(whi, xlo[kh], acc, 0, 0, 0);
        }
        const int c0 = dt * 16 + g * 4;
        const float4 b4 = *(const float4*)(bias + c0);
        const float sc = (m == 0) ? QSCALE : 1.0f;
        b4v pv;
        pv[0] = (__bf16)((acc[0] + b4.x) * sc);
        pv[1] = (__bf16)((acc[1] + b4.y) * sc);
        pv[2] = (__bf16)((acc[2] + b4.z) * sc);
        pv[3] = (__bf16)((acc[3] + b4.w) * sc);
        if (m == 0) {
            *(b4v*)(Qb + (rb + r) * DM + c0) = pv;
        } else {
            const int row = rb + r, t = row >> 5, row32 = row & 31;
            const int ch  = dt * 2 + (g >> 1);
            const int b2  = ((row32 >> 4) << 1) | (ch >> 2);
            *(b4v*)(Ks + t * 2048 + b2 * 512 + (ch & 3) * 128
                       + (row32 & 15) * 8 + (g & 1) * 4) = pv;
        }
    }

    // ---- V (m=2): mfma(X, W) -> D[x-row(kv)][feat] ----
    {
        f4 acc = {0.f, 0.f, 0.f, 0.f};
        #pragma unroll
        for (int kh = 0; kh < 2; ++kh) {
            const bfrag whi = *(const bfrag*)(Whi + 2 * 4096 + (dt * 16 + r) * DM + kh * 32 + g * 8);
            const bfrag wlo = *(const bfrag*)(Wlo + 2 * 4096 + (dt * 16 + r) * DM + kh * 32 + g * 8);
            acc = __builtin_amdgcn_mfma_f32_16x16x32_bf16(xhi[kh], whi, acc, 0, 0, 0);
            acc = __builtin_amdgcn_mfma_f32_16x16x32_bf16(xlo[kh], whi, acc, 0, 0, 0);
            acc = __builtin_amdgcn_mfma_f32_16x16x32_bf16(xhi[kh], wlo, acc, 0, 0, 0);
        }
        const int d  = dt * 16 + r;
        const float bd = bv[d];
        const int L0 = (rb & 31) + g * 4;
        const int P0 = ((L0 & 15) >> 2) * 8 + (L0 >> 4) * 4;
        const int t  = rb >> 5;
        b4v pv;
        pv[0] = (__bf16)(acc[0] + bd);
        pv[1] = (__bf16)(acc[1] + bd);
        pv[2] = (__bf16)(acc[2] + bd);
        pv[3] = (__bf16)(acc[3] + bd);
        *(b4v*)(Vg + t * 2048 + (d >> 4) * 512 + (P0 >> 3) * 128
                   + (d & 15) * 8 + (P0 & 7)) = pv;
    }
}

// ---------------------------------------------------------------------------
// Kernel 2: flash attention partials, Q-reuse=4.
// Grid 512 = (fam 0..127 -> qt via pairing: 64 q-rows) x (g4 0..3 kv slice).
// Per step: stage 4 kv tiles (32 KB, double-buffered, linear global_load_lds),
// wave w computes tile j0+w against FOUR 16-row q-subtiles -> staging bytes
// and ds_reads per cell halve vs round 10. Masking is generic per-element
// kv<=q cndmask (handles diagonal AND overrun tiles; NaN-safe select).
// Swapped QK^T + sigma PV (verified). exp2 with pre-folded scale.
// ---------------------------------------------------------------------------
__global__ __launch_bounds__(256)
__attribute__((amdgpu_waves_per_eu(2)))
void flash_attn(
    const __bf16* __restrict__ Qb, const __bf16* __restrict__ Ks,
    const __bf16* __restrict__ Vg,
    float* __restrict__ Opart, float* __restrict__ Lpart)
{
    __shared__ __align__(16) unsigned char smem[73728];  // 2x32K stage | 70.7K epilogue

    const int tid  = threadIdx.x;
    const int lane = tid & 63;
    const int wid  = tid >> 6;               // 0..3
    const int b    = blockIdx.x;
    const int fam  = b >> 2;                 // 0..127
    const int g4   = b & 3;                  // kv slice
    const int qt   = (fam < 64) ? (127 - fam) : (fam - 64);  // pair big+small
    const int qbase = qt * 64;
    const int gq = lane >> 4;                // 0..3
    const int r  = lane & 15;

    // Q fragments for four 16-row subtiles
    bfrag qf[4][2];
    #pragma unroll
    for (int sub = 0; sub < 4; ++sub)
        #pragma unroll
        for (int kh = 0; kh < 2; ++kh)
            qf[sub][kh] = *(const bfrag*)(Qb + (qbase + sub * 16 + r) * DM + kh * 32 + gq * 8);

    f4 o[4][4] = {};
    float ls[4] = {0.f, 0.f, 0.f, 0.f};

    const int ntiles = 2 * qt + 2;           // kv tiles needed by this q-block
    const int f0 = g4 * 4;
    const int nsteps = (ntiles > f0) ? ((ntiles - f0 + 15) >> 4) : 0;

    const char* Kbb = (const char*)Ks;
    const char* Vbb = (const char*)Vg;
    const int lo16 = lane << 4;

    auto stage = [&](int s, int buf) {
        const long long base = (long long)(f0 + s * 16) * 4096;
        #pragma unroll
        for (int jr = 0; jr < 4; ++jr) {
            const int st = jr * 4 + wid;     // 1-KB stripe 0..15
            GLOAD16(Kbb + base + st * 1024 + lo16, smem + buf * 32768 + st * 1024);
            GLOAD16(Vbb + base + st * 1024 + lo16, smem + buf * 32768 + 16384 + st * 1024);
        }
    };

    int cur = 0;
    if (nsteps > 0) stage(0, 0);
    __syncthreads();

    for (int s = 0; s < nsteps; ++s) {
        if (s + 1 < nsteps) stage(s + 1, cur ^ 1);   // prefetch next step

        const unsigned char* Kr = smem + cur * 32768 + wid * 4096;
        const unsigned char* Vr = Kr + 16384;
        const bfrag kf0 = *(const bfrag*)(Kr + lo16);
        const bfrag kf1 = *(const bfrag*)(Kr + 1024 + lo16);
        const bfrag kf2 = *(const bfrag*)(Kr + 2048 + lo16);
        const bfrag kf3 = *(const bfrag*)(Kr + 3072 + lo16);
        bfrag vf[4];
        #pragma unroll
        for (int dt = 0; dt < 4; ++dt)
            vf[dt] = *(const bfrag*)(Vr + dt * 1024 + lo16);

        const int j = f0 + s * 16 + wid;     // this wave's kv tile
        const int kvb = j * 32 + gq * 4;

        #pragma unroll
        for (int sub = 0; sub < 4; ++sub) {
            f4 sh0 = {}, sh1 = {};           // S'[kv][q], swapped operands
            sh0 = __builtin_amdgcn_mfma_f32_16x16x32_bf16(kf0, qf[sub][0], sh0, 0, 0, 0);
            sh0 = __builtin_amdgcn_mfma_f32_16x16x32_bf16(kf1, qf[sub][1], sh0, 0, 0, 0);
            sh1 = __builtin_amdgcn_mfma_f32_16x16x32_bf16(kf2, qf[sub][0], sh1, 0, 0, 0);
            sh1 = __builtin_amdgcn_mfma_f32_16x16x32_bf16(kf3, qf[sub][1], sh1, 0, 0, 0);

            const int qg = qbase + sub * 16 + r;
            float p0[4], p1[4];
            #pragma unroll
            for (int e = 0; e < 4; ++e) {
                p0[e] = (kvb + e      <= qg) ? exp2f(sh0[e]) : 0.f;
                p1[e] = (kvb + e + 16 <= qg) ? exp2f(sh1[e]) : 0.f;
            }
            ls[sub] += (p0[0] + p0[1]) + (p0[2] + p0[3])
                     + (p1[0] + p1[1]) + (p1[2] + p1[3]);

            PW pu;                           // sigma pack: slots 0-3 <- h0, 4-7 <- h1
            pu.w[0] = pack_bf16(p0[0], p0[1]); pu.w[1] = pack_bf16(p0[2], p0[3]);
            pu.w[2] = pack_bf16(p1[0], p1[1]); pu.w[3] = pack_bf16(p1[2], p1[3]);

            #pragma unroll
            for (int dt = 0; dt < 4; ++dt)
                o[sub][dt] = __builtin_amdgcn_mfma_f32_16x16x32_bf16(pu.v, vf[dt], o[sub][dt], 0, 0, 0);
        }

        __syncthreads();                     // reads done + prefetch landed
        cur ^= 1;
    }

    // ---- epilogue: combine 4 waves' partials (reuse smem) ----
    float* Ol  = (float*)smem;               // [4][64][68] = 69632 B
    float* Lsm = (float*)(smem + 69632);     // [4][64]
    #pragma unroll
    for (int sub = 0; sub < 4; ++sub) {
        ls[sub] += __shfl_xor(ls[sub], 16, 64);
        ls[sub] += __shfl_xor(ls[sub], 32, 64);
        if (lane < 16) Lsm[wid * 64 + sub * 16 + r] = ls[sub];
        #pragma unroll
        for (int dt = 0; dt < 4; ++dt)
            #pragma unroll
            for (int e = 0; e < 4; ++e)
                Ol[(wid * 64 + sub * 16 + gq * 4 + e) * 68 + dt * 16 + r] = o[sub][dt][e];
    }
    __syncthreads();

    for (int i = tid; i < 64 * 64; i += 256) {
        const int row = i >> 6, col = i & 63;
        const float sum = Ol[(row) * 68 + col] + Ol[(64 + row) * 68 + col]
                        + Ol[(128 + row) * 68 + col] + Ol[(192 + row) * 68 + col];
        Opart[((long long)g4 * SEQ + qbase + row) * DM + col] = sum;
    }
    if (tid < 64) {
        const float l = Lsm[tid] + Lsm[64 + tid] + Lsm[128 + tid] + Lsm[192 + tid];
        Lpart[g4 * SEQ + qbase + tid] = l;
    }
}

// ---------------------------------------------------------------------------
// Kernel 3: out = (O0+O1+O2+O3) / (L0+L1+L2+L3)
// ---------------------------------------------------------------------------
__global__ __launch_bounds__(256) void normalize(
    const float* __restrict__ Opart, const float* __restrict__ Lpart,
    float* __restrict__ out)
{
    const int i = blockIdx.x * 256 + threadIdx.x;     // f4 index
    const f4* O = (const f4*)Opart;
    const int N = SEQ * DM / 4;
    const int row = i >> 4;
    const f4 a0 = O[i], a1 = O[N + i], a2 = O[2 * N + i], a3 = O[3 * N + i];
    const float l = (Lpart[row] + Lpart[SEQ + row])
                  + (Lpart[2 * SEQ + row] + Lpart[3 * SEQ + row]);
    const float inv = 1.0f / l;
    f4 res;
    #pragma unroll
    for (int e = 0; e < 4; ++e) res[e] = ((a0[e] + a1[e]) + (a2[e] + a3[e])) * inv;
    ((f4*)out)[i] = res;
}

extern "C" void kernel_launch(void* const* d_in, const int* in_sizes, int n_in,
                              void* d_out, int out_size, void* d_ws, size_t ws_size,
                              hipStream_t stream)
{
    (void)in_sizes; (void)n_in; (void)out_size; (void)ws_size;
    const float* x  = (const float*)d_in[0];
    const float* wq = (const float*)d_in[1];
    const float* bq = (const float*)d_in[2];
    const float* wk = (const float*)d_in[3];
    const float* bk = (const float*)d_in[4];
    const float* wv = (const float*)d_in[5];
    const float* bv = (const float*)d_in[6];
    float* out = (float*)d_out;

    __bf16* Qb  = (__bf16*)d_ws;                      // [S][64] bf16, 1 MB
    __bf16* Ks  = Qb + SEQ * DM;                      // tile-major K, 1 MB
    __bf16* Vg  = Ks + SEQ * DM;                      // tile-major sigma V, 1 MB
    __bf16* Xhi = Vg + SEQ * DM;                      // 1 MB
    __bf16* Xlo = Xhi + SEQ * DM;                     // 1 MB
    __bf16* Whi = Xlo + SEQ * DM;                     // 24 KB
    __bf16* Wlo = Whi + 3 * DM * DM;                  // 24 KB
    float*  Opart = (float*)(Wlo + 3 * DM * DM);      // [4][S][64] f32, 8 MB
    float*  Lpart = Opart + 4 * SEQ * DM;             // [4][S] f32, 128 KB

    presplit<<<(SEQ * DM / 4 + 3 * DM * DM / 4 + 255) / 256, 256, 0, stream>>>(
        x, wq, wk, wv, Xhi, Xlo, Whi, Wlo);
    qkv_proj<<<512, 256, 0, stream>>>(Xhi, Xlo, Whi, Wlo, bq, bk, bv, Qb, Ks, Vg);
    flash_attn<<<512, 256, 0, stream>>>(Qb, Ks, Vg, Opart, Lpart);
    normalize<<<SEQ * DM / 4 / 256, 256, 0, stream>>>(Opart, Lpart, out);
}

// Round 12
// 37.195 us; speedup vs baseline: 1.3653x; 1.3653x over previous
//
#include <hip/hip_runtime.h>

#define SEQ 8192
#define DM 64

typedef __bf16 bfrag __attribute__((ext_vector_type(8)));   // MFMA A/B operand
typedef __bf16 b4v   __attribute__((ext_vector_type(4)));   // 8-byte bf16 pack
typedef float  f4    __attribute__((ext_vector_type(4)));   // MFMA C/D operand

union PW { int w[4]; bfrag v; };

// fold 1/sqrt(64) * log2(e) into Q so softmax is a bare v_exp_f32 (2^x)
#define QSCALE 0.1803368801111204f

#define GLOAD16(gsrc, ldst)                                                \
    __builtin_amdgcn_global_load_lds(                                      \
        (const __attribute__((address_space(1))) unsigned int*)(gsrc),     \
        (__attribute__((address_space(3))) unsigned int*)(ldst), 16, 0, 0)

__device__ inline float fexp2(float x) {        // guaranteed native v_exp_f32
    float y;
    asm("v_exp_f32 %0, %1" : "=v"(y) : "v"(x));
    return y;
}

__device__ inline int pack_bf16(float a, float b) {
    const __bf16 ba = (__bf16)a, bb = (__bf16)b;
    const unsigned short ua = __builtin_bit_cast(unsigned short, ba);
    const unsigned short ub = __builtin_bit_cast(unsigned short, bb);
    return (int)(((unsigned)ub << 16) | (unsigned)ua);
}

// split f32 x8 into bf16 hi + bf16 lo (residual) for near-fp32 MFMA matmul
__device__ inline void split8(const float* __restrict__ p, bfrag& hi, bfrag& lo) {
    #pragma unroll
    for (int e = 0; e < 8; ++e) {
        const float v = p[e];
        const __bf16 h = (__bf16)v;
        hi[e] = h;
        lo[e] = (__bf16)(v - (float)h);
    }
}

// ---------------------------------------------------------------------------
// Kernel 1 (MFMA): 6144 wave-tasks = (m, 16-row x-tile rt, dt). 1536 blocks
// x 4 waves = 24 waves/CU (latency hidden). hi/lo split (~fp32 accuracy).
// Store layouts byte-identical to the round-10-verified ones:
//  Qb row-major (scaled QSCALE); Ks/Vg tile-major lane-linear.
// ---------------------------------------------------------------------------
__global__ __launch_bounds__(256) void qkv_proj(
    const float* __restrict__ x,
    const float* __restrict__ wq, const float* __restrict__ bq,
    const float* __restrict__ wk, const float* __restrict__ bk,
    const float* __restrict__ wv, const float* __restrict__ bv,
    __bf16* __restrict__ Qb, __bf16* __restrict__ Ks, __bf16* __restrict__ Vg)
{
    const int lane = threadIdx.x & 63;
    const int wid  = threadIdx.x >> 6;
    const int task = blockIdx.x * 4 + wid;      // 0..6143
    const int m    = task >> 11;                // 0..2
    const int rest = task & 2047;
    const int rt   = rest >> 2;                 // 0..511
    const int dt   = rest & 3;                  // 0..3
    const int rb   = rt << 4;
    const int g = lane >> 4, r = lane & 15;

    const float* w = (m == 0) ? wq : (m == 1) ? wk : wv;

    bfrag xhi[2], xlo[2];
    #pragma unroll
    for (int kh = 0; kh < 2; ++kh)
        split8(x + (rb + r) * DM + kh * 32 + g * 8, xhi[kh], xlo[kh]);
    bfrag whi[2], wlo[2];
    #pragma unroll
    for (int kh = 0; kh < 2; ++kh)
        split8(w + (dt * 16 + r) * DM + kh * 32 + g * 8, whi[kh], wlo[kh]);

    if (m < 2) {                                // Q/K: mfma(W, X) -> D[feat][x-row]
        f4 acc = {0.f, 0.f, 0.f, 0.f};
        #pragma unroll
        for (int kh = 0; kh < 2; ++kh) {
            acc = __builtin_amdgcn_mfma_f32_16x16x32_bf16(whi[kh], xhi[kh], acc, 0, 0, 0);
            acc = __builtin_amdgcn_mfma_f32_16x16x32_bf16(wlo[kh], xhi[kh], acc, 0, 0, 0);
            acc = __builtin_amdgcn_mfma_f32_16x16x32_bf16(whi[kh], xlo[kh], acc, 0, 0, 0);
        }
        const float* bias = (m == 0) ? bq : bk;
        const int c0 = dt * 16 + g * 4;         // 4 consecutive features
        const float4 b4 = *(const float4*)(bias + c0);
        const float sc = (m == 0) ? QSCALE : 1.0f;
        b4v pv;
        pv[0] = (__bf16)((acc[0] + b4.x) * sc);
        pv[1] = (__bf16)((acc[1] + b4.y) * sc);
        pv[2] = (__bf16)((acc[2] + b4.z) * sc);
        pv[3] = (__bf16)((acc[3] + b4.w) * sc);
        if (m == 0) {
            *(b4v*)(Qb + (rb + r) * DM + c0) = pv;
        } else {
            const int row = rb + r, t = row >> 5, row32 = row & 31;
            const int ch  = dt * 2 + (g >> 1);
            const int b2  = ((row32 >> 4) << 1) | (ch >> 2);
            *(b4v*)(Ks + t * 2048 + b2 * 512 + (ch & 3) * 128
                       + (row32 & 15) * 8 + (g & 1) * 4) = pv;
        }
    } else {                                    // V: mfma(X, W) -> D[x-row(kv)][feat]
        f4 acc = {0.f, 0.f, 0.f, 0.f};
        #pragma unroll
        for (int kh = 0; kh < 2; ++kh) {
            acc = __builtin_amdgcn_mfma_f32_16x16x32_bf16(xhi[kh], whi[kh], acc, 0, 0, 0);
            acc = __builtin_amdgcn_mfma_f32_16x16x32_bf16(xlo[kh], whi[kh], acc, 0, 0, 0);
            acc = __builtin_amdgcn_mfma_f32_16x16x32_bf16(xhi[kh], wlo[kh], acc, 0, 0, 0);
        }
        const int d  = dt * 16 + r;
        const float bd = bv[d];
        const int L0 = (rb & 31) + g * 4;       // kv rows rb + g*4 + e
        const int P0 = ((L0 & 15) >> 2) * 8 + (L0 >> 4) * 4;  // sigma slot base
        const int t  = rb >> 5;
        b4v pv;
        pv[0] = (__bf16)(acc[0] + bd);
        pv[1] = (__bf16)(acc[1] + bd);
        pv[2] = (__bf16)(acc[2] + bd);
        pv[3] = (__bf16)(acc[3] + bd);
        *(b4v*)(Vg + t * 2048 + (d >> 4) * 512 + (P0 >> 3) * 128
                   + (d & 15) * 8 + (P0 & 7)) = pv;
    }
}

// ---------------------------------------------------------------------------
// Kernel 2: flash attention partials, K-only LDS staging (34.8 KB total ->
// 4 blocks/CU = 4 waves/SIMD). Grid 1024 = fam(0..255) x g4(0..3 kv slice);
// balanced qt map: CU's 4 resident blocks sum to ~constant work.
// Slice g4 covers kv tiles j == {4g4..4g4+3} (mod 16); per step: stage 4 K
// tiles (16 KB dbuf, linear global_load_lds), V read DIRECT from global Vg
// (uniform+lane*16, coalesced, L2-resident), issued before the stage so the
// compiler's V-wait leaves the K prefetch in flight.
// Swapped QK^T + sigma PV + generic kv<=q masking (all verified r5-r11).
// ---------------------------------------------------------------------------
__global__ __launch_bounds__(256)
__attribute__((amdgpu_waves_per_eu(4)))
void flash_attn(
    const __bf16* __restrict__ Qb, const __bf16* __restrict__ Ks,
    const __bf16* __restrict__ Vg,
    float* __restrict__ Opart, float* __restrict__ Lpart)
{
    __shared__ __align__(16) unsigned char smem[34816]; // 2x16K stage | 34.3K epi

    const int tid  = threadIdx.x;
    const int lane = tid & 63;
    const int wid  = tid >> 6;               // 0..3
    const int b    = blockIdx.x;
    const int fam  = b >> 2;                 // 0..255
    const int g4   = b & 3;                  // kv slice
    const int grp  = fam >> 6, hh = fam & 63;
    const int qt   = (grp == 0) ? (255 - hh) : (grp == 1) ? hh
                   : (grp == 2) ? (191 - hh) : (64 + hh);   // 4-way balanced
    const int qbase = qt * 32;
    const int gq = lane >> 4;                // 0..3
    const int r  = lane & 15;
    const int lo16 = lane << 4;

    bfrag qf[2][2];
    #pragma unroll
    for (int sub = 0; sub < 2; ++sub)
        #pragma unroll
        for (int kh = 0; kh < 2; ++kh)
            qf[sub][kh] = *(const bfrag*)(Qb + (qbase + sub * 16 + r) * DM + kh * 32 + gq * 8);

    f4 o[2][4] = {};
    float ls[2] = {0.f, 0.f};

    const int ntiles = qt + 1;
    const int f0 = g4 * 4;
    const int nsteps = (ntiles > f0) ? ((ntiles - f0 + 15) >> 4) : 0;

    const char* Kbb = (const char*)Ks;
    const char* Vbb = (const char*)Vg;

    auto stage = [&](int s, int buf) {
        const int base = (f0 + s * 16) * 4096;
        #pragma unroll
        for (int jr = 0; jr < 4; ++jr) {
            const int st = jr * 4 + wid;     // 1-KB stripe 0..15
            GLOAD16(Kbb + base + st * 1024 + lo16, smem + buf * 16384 + st * 1024);
        }
    };

    int cur = 0;
    if (nsteps > 0) stage(0, 0);
    __syncthreads();

    for (int s = 0; s < nsteps; ++s) {
        const int j = f0 + s * 16 + wid;     // this wave's kv tile
        // V direct loads FIRST (so their wait doesn't drain the K prefetch)
        bfrag vf[4];
        #pragma unroll
        for (int dt = 0; dt < 4; ++dt)
            vf[dt] = *(const bfrag*)(Vbb + j * 4096 + dt * 1024 + lo16);
        if (s + 1 < nsteps) stage(s + 1, cur ^ 1);   // K prefetch for next step

        const unsigned char* Kr = smem + cur * 16384 + wid * 4096;
        const bfrag kf0 = *(const bfrag*)(Kr + lo16);
        const bfrag kf1 = *(const bfrag*)(Kr + 1024 + lo16);
        const bfrag kf2 = *(const bfrag*)(Kr + 2048 + lo16);
        const bfrag kf3 = *(const bfrag*)(Kr + 3072 + lo16);

        const int kvb = j * 32 + gq * 4;
        #pragma unroll
        for (int sub = 0; sub < 2; ++sub) {
            f4 sh0 = {}, sh1 = {};           // S'[kv][q], swapped operands
            sh0 = __builtin_amdgcn_mfma_f32_16x16x32_bf16(kf0, qf[sub][0], sh0, 0, 0, 0);
            sh0 = __builtin_amdgcn_mfma_f32_16x16x32_bf16(kf1, qf[sub][1], sh0, 0, 0, 0);
            sh1 = __builtin_amdgcn_mfma_f32_16x16x32_bf16(kf2, qf[sub][0], sh1, 0, 0, 0);
            sh1 = __builtin_amdgcn_mfma_f32_16x16x32_bf16(kf3, qf[sub][1], sh1, 0, 0, 0);

            const int qg = qbase + sub * 16 + r;
            float p0[4], p1[4];
            #pragma unroll
            for (int e = 0; e < 4; ++e) {
                p0[e] = (kvb + e      <= qg) ? fexp2(sh0[e]) : 0.f;
                p1[e] = (kvb + e + 16 <= qg) ? fexp2(sh1[e]) : 0.f;
            }
            ls[sub] += (p0[0] + p0[1]) + (p0[2] + p0[3])
                     + (p1[0] + p1[1]) + (p1[2] + p1[3]);

            PW pu;                           // sigma pack: slots 0-3 <- h0, 4-7 <- h1
            pu.w[0] = pack_bf16(p0[0], p0[1]); pu.w[1] = pack_bf16(p0[2], p0[3]);
            pu.w[2] = pack_bf16(p1[0], p1[1]); pu.w[3] = pack_bf16(p1[2], p1[3]);

            #pragma unroll
            for (int dt = 0; dt < 4; ++dt)
                o[sub][dt] = __builtin_amdgcn_mfma_f32_16x16x32_bf16(pu.v, vf[dt], o[sub][dt], 0, 0, 0);
        }

        __syncthreads();                     // reads done + K prefetch landed
        cur ^= 1;
    }

    // ---- epilogue: combine 4 waves' partials (reuse smem) ----
    float* Ol  = (float*)smem;               // [4][32][66] = 33792 B
    float* Lsm = (float*)(smem + 33792);     // [4][32]
    #pragma unroll
    for (int sub = 0; sub < 2; ++sub) {
        ls[sub] += __shfl_xor(ls[sub], 16, 64);
        ls[sub] += __shfl_xor(ls[sub], 32, 64);
        if (lane < 16) Lsm[wid * 32 + sub * 16 + r] = ls[sub];
        #pragma unroll
        for (int dt = 0; dt < 4; ++dt)
            #pragma unroll
            for (int e = 0; e < 4; ++e)
                Ol[(wid * 32 + sub * 16 + gq * 4 + e) * 66 + dt * 16 + r] = o[sub][dt][e];
    }
    __syncthreads();

    for (int i = tid; i < 32 * 64; i += 256) {
        const int row = i >> 6, col = i & 63;
        const float sum = Ol[(row) * 66 + col] + Ol[(32 + row) * 66 + col]
                        + Ol[(64 + row) * 66 + col] + Ol[(96 + row) * 66 + col];
        Opart[((long long)g4 * SEQ + qbase + row) * DM + col] = sum;
    }
    if (tid < 32) {
        const float l = Lsm[tid] + Lsm[32 + tid] + Lsm[64 + tid] + Lsm[96 + tid];
        Lpart[g4 * SEQ + qbase + tid] = l;
    }
}

// ---------------------------------------------------------------------------
// Kernel 3: out = (O0+O1+O2+O3) / (L0+L1+L2+L3)
// ---------------------------------------------------------------------------
__global__ __launch_bounds__(256) void normalize(
    const float* __restrict__ Opart, const float* __restrict__ Lpart,
    float* __restrict__ out)
{
    const int i = blockIdx.x * 256 + threadIdx.x;     // f4 index
    const f4* O = (const f4*)Opart;
    const int N = SEQ * DM / 4;
    const int row = i >> 4;
    const f4 a0 = O[i], a1 = O[N + i], a2 = O[2 * N + i], a3 = O[3 * N + i];
    const float l = (Lpart[row] + Lpart[SEQ + row])
                  + (Lpart[2 * SEQ + row] + Lpart[3 * SEQ + row]);
    const float inv = 1.0f / l;
    f4 res;
    #pragma unroll
    for (int e = 0; e < 4; ++e) res[e] = ((a0[e] + a1[e]) + (a2[e] + a3[e])) * inv;
    ((f4*)out)[i] = res;
}

extern "C" void kernel_launch(void* const* d_in, const int* in_sizes, int n_in,
                              void* d_out, int out_size, void* d_ws, size_t ws_size,
                              hipStream_t stream)
{
    (void)in_sizes; (void)n_in; (void)out_size; (void)ws_size;
    const float* x  = (const float*)d_in[0];
    const float* wq = (const float*)d_in[1];
    const float* bq = (const float*)d_in[2];
    const float* wk = (const float*)d_in[3];
    const float* bk = (const float*)d_in[4];
    const float* wv = (const float*)d_in[5];
    const float* bv = (const float*)d_in[6];
    float* out = (float*)d_out;

    __bf16* Qb = (__bf16*)d_ws;                       // [S][64] bf16, 1 MB
    __bf16* Ks = Qb + SEQ * DM;                       // tile-major K, 1 MB
    __bf16* Vg = Ks + SEQ * DM;                       // tile-major sigma V, 1 MB
    float*  Opart = (float*)(Vg + SEQ * DM);          // [4][S][64] f32, 8 MB
    float*  Lpart = Opart + 4 * SEQ * DM;             // [4][S] f32, 128 KB

    qkv_proj<<<1536, 256, 0, stream>>>(x, wq, bq, wk, bk, wv, bv, Qb, Ks, Vg);
    flash_attn<<<1024, 256, 0, stream>>>(Qb, Ks, Vg, Opart, Lpart);
    normalize<<<SEQ * DM / 4 / 256, 256, 0, stream>>>(Opart, Lpart, out);
}

// Round 13
// 35.765 us; speedup vs baseline: 1.4199x; 1.0400x over previous
//
#include <hip/hip_runtime.h>

#define SEQ 8192
#define DM 64

typedef __bf16 bfrag __attribute__((ext_vector_type(8)));   // MFMA A/B operand
typedef __bf16 b4v   __attribute__((ext_vector_type(4)));   // 8-byte bf16 pack
typedef float  f4    __attribute__((ext_vector_type(4)));   // MFMA C/D operand

union PW { int w[4]; bfrag v; };

// fold 1/sqrt(64) * log2(e) into Q so softmax is a bare v_exp_f32 (2^x)
#define QSCALE 0.1803368801111204f

#define GLOAD16(gsrc, ldst)                                                \
    __builtin_amdgcn_global_load_lds(                                      \
        (const __attribute__((address_space(1))) unsigned int*)(gsrc),     \
        (__attribute__((address_space(3))) unsigned int*)(ldst), 16, 0, 0)

__device__ inline float fexp2(float x) {        // guaranteed native v_exp_f32
    float y;
    asm("v_exp_f32 %0, %1" : "=v"(y) : "v"(x));
    return y;
}

__device__ inline int cvtpk(float a, float b) { // packed 2xbf16 in one instr
    int d;
    asm("v_cvt_pk_bf16_f32 %0, %1, %2" : "=v"(d) : "v"(a), "v"(b));
    return d;
}

// split f32 x8 into bf16 hi + bf16 lo (residual) for near-fp32 MFMA matmul
__device__ inline void split8(const float* __restrict__ p, bfrag& hi, bfrag& lo) {
    #pragma unroll
    for (int e = 0; e < 8; ++e) {
        const float v = p[e];
        const __bf16 h = (__bf16)v;
        hi[e] = h;
        lo[e] = (__bf16)(v - (float)h);
    }
}

// ---------------------------------------------------------------------------
// Kernel 1 (MFMA): 6144 wave-tasks = (m, 16-row x-tile rt, dt). 1536 blocks
// x 4 waves = 24 waves/CU. hi/lo split (~fp32 accuracy). Unchanged from r12.
// ---------------------------------------------------------------------------
__global__ __launch_bounds__(256) void qkv_proj(
    const float* __restrict__ x,
    const float* __restrict__ wq, const float* __restrict__ bq,
    const float* __restrict__ wk, const float* __restrict__ bk,
    const float* __restrict__ wv, const float* __restrict__ bv,
    __bf16* __restrict__ Qb, __bf16* __restrict__ Ks, __bf16* __restrict__ Vg)
{
    const int lane = threadIdx.x & 63;
    const int wid  = threadIdx.x >> 6;
    const int task = blockIdx.x * 4 + wid;      // 0..6143
    const int m    = task >> 11;                // 0..2
    const int rest = task & 2047;
    const int rt   = rest >> 2;                 // 0..511
    const int dt   = rest & 3;                  // 0..3
    const int rb   = rt << 4;
    const int g = lane >> 4, r = lane & 15;

    const float* w = (m == 0) ? wq : (m == 1) ? wk : wv;

    bfrag xhi[2], xlo[2];
    #pragma unroll
    for (int kh = 0; kh < 2; ++kh)
        split8(x + (rb + r) * DM + kh * 32 + g * 8, xhi[kh], xlo[kh]);
    bfrag whi[2], wlo[2];
    #pragma unroll
    for (int kh = 0; kh < 2; ++kh)
        split8(w + (dt * 16 + r) * DM + kh * 32 + g * 8, whi[kh], wlo[kh]);

    if (m < 2) {                                // Q/K: mfma(W, X) -> D[feat][x-row]
        f4 acc = {0.f, 0.f, 0.f, 0.f};
        #pragma unroll
        for (int kh = 0; kh < 2; ++kh) {
            acc = __builtin_amdgcn_mfma_f32_16x16x32_bf16(whi[kh], xhi[kh], acc, 0, 0, 0);
            acc = __builtin_amdgcn_mfma_f32_16x16x32_bf16(wlo[kh], xhi[kh], acc, 0, 0, 0);
            acc = __builtin_amdgcn_mfma_f32_16x16x32_bf16(whi[kh], xlo[kh], acc, 0, 0, 0);
        }
        const float* bias = (m == 0) ? bq : bk;
        const int c0 = dt * 16 + g * 4;         // 4 consecutive features
        const float4 b4 = *(const float4*)(bias + c0);
        const float sc = (m == 0) ? QSCALE : 1.0f;
        b4v pv;
        pv[0] = (__bf16)((acc[0] + b4.x) * sc);
        pv[1] = (__bf16)((acc[1] + b4.y) * sc);
        pv[2] = (__bf16)((acc[2] + b4.z) * sc);
        pv[3] = (__bf16)((acc[3] + b4.w) * sc);
        if (m == 0) {
            *(b4v*)(Qb + (rb + r) * DM + c0) = pv;
        } else {
            const int row = rb + r, t = row >> 5, row32 = row & 31;
            const int ch  = dt * 2 + (g >> 1);
            const int b2  = ((row32 >> 4) << 1) | (ch >> 2);
            *(b4v*)(Ks + t * 2048 + b2 * 512 + (ch & 3) * 128
                       + (row32 & 15) * 8 + (g & 1) * 4) = pv;
        }
    } else {                                    // V: mfma(X, W) -> D[x-row(kv)][feat]
        f4 acc = {0.f, 0.f, 0.f, 0.f};
        #pragma unroll
        for (int kh = 0; kh < 2; ++kh) {
            acc = __builtin_amdgcn_mfma_f32_16x16x32_bf16(xhi[kh], whi[kh], acc, 0, 0, 0);
            acc = __builtin_amdgcn_mfma_f32_16x16x32_bf16(xlo[kh], whi[kh], acc, 0, 0, 0);
            acc = __builtin_amdgcn_mfma_f32_16x16x32_bf16(xhi[kh], wlo[kh], acc, 0, 0, 0);
        }
        const int d  = dt * 16 + r;
        const float bd = bv[d];
        const int L0 = (rb & 31) + g * 4;       // kv rows rb + g*4 + e
        const int P0 = ((L0 & 15) >> 2) * 8 + (L0 >> 4) * 4;  // sigma slot base
        const int t  = rb >> 5;
        b4v pv;
        pv[0] = (__bf16)(acc[0] + bd);
        pv[1] = (__bf16)(acc[1] + bd);
        pv[2] = (__bf16)(acc[2] + bd);
        pv[3] = (__bf16)(acc[3] + bd);
        *(b4v*)(Vg + t * 2048 + (d >> 4) * 512 + (P0 >> 3) * 128
                   + (d & 15) * 8 + (P0 & 7)) = pv;
    }
}

// ---------------------------------------------------------------------------
// Kernel 2: flash attention partials. Structure of r12 (K-only dbuf staging,
// 4 blocks/CU, V direct, balanced qt map) plus:
//  - per-wave guard j<=qt: overrun tiles skip ALL work (waves idle at barrier)
//  - diagonal peel: only j==qt pays cmp+cndmask; j<qt is bare exp
//  - row-sum via ones-MFMA (matrix pipe) instead of 14 VALU adds
//  - v_cvt_pk_bf16_f32 for P packing
// ---------------------------------------------------------------------------
__global__ __launch_bounds__(256)
__attribute__((amdgpu_waves_per_eu(4)))
void flash_attn(
    const __bf16* __restrict__ Qb, const __bf16* __restrict__ Ks,
    const __bf16* __restrict__ Vg,
    float* __restrict__ Opart, float* __restrict__ Lpart)
{
    __shared__ __align__(16) unsigned char smem[34816]; // 2x16K stage | 34.3K epi

    const int tid  = threadIdx.x;
    const int lane = tid & 63;
    const int wid  = tid >> 6;               // 0..3
    const int b    = blockIdx.x;
    const int fam  = b >> 2;                 // 0..255
    const int g4   = b & 3;                  // kv slice
    const int grp  = fam >> 6, hh = fam & 63;
    const int qt   = (grp == 0) ? (255 - hh) : (grp == 1) ? hh
                   : (grp == 2) ? (191 - hh) : (64 + hh);   // 4-way balanced
    const int qbase = qt * 32;
    const int gq = lane >> 4;                // 0..3
    const int r  = lane & 15;
    const int lo16 = lane << 4;

    bfrag qf[2][2];
    #pragma unroll
    for (int sub = 0; sub < 2; ++sub)
        #pragma unroll
        for (int kh = 0; kh < 2; ++kh)
            qf[sub][kh] = *(const bfrag*)(Qb + (qbase + sub * 16 + r) * DM + kh * 32 + gq * 8);

    bfrag ones;                              // B-operand of the row-sum MFMA
    #pragma unroll
    for (int e = 0; e < 8; ++e) ones[e] = (__bf16)1.0f;

    f4 o[2][4] = {};
    f4 lsacc[2] = {};                        // row-sums via MFMA (all cols equal)

    const int ntiles = qt + 1;
    const int f0 = g4 * 4;
    const int nsteps = (ntiles > f0) ? ((ntiles - f0 + 15) >> 4) : 0;

    const char* Kbb = (const char*)Ks;
    const char* Vbb = (const char*)Vg;

    auto stage = [&](int s, int buf) {
        const int base = (f0 + s * 16) * 4096;
        #pragma unroll
        for (int jr = 0; jr < 4; ++jr) {
            const int st = jr * 4 + wid;     // 1-KB stripe 0..15
            GLOAD16(Kbb + base + st * 1024 + lo16, smem + buf * 16384 + st * 1024);
        }
    };

    int cur = 0;
    if (nsteps > 0) stage(0, 0);
    __syncthreads();

    for (int s = 0; s < nsteps; ++s) {
        const int j = f0 + s * 16 + wid;     // this wave's kv tile (uniform)
        const bool live = (j <= qt);
        bfrag vf[4];
        if (live) {                          // V direct, issued BEFORE stage so
            #pragma unroll                   // its wait leaves K prefetch in flight
            for (int dt = 0; dt < 4; ++dt)
                vf[dt] = *(const bfrag*)(Vbb + j * 4096 + dt * 1024 + lo16);
        }
        if (s + 1 < nsteps) stage(s + 1, cur ^ 1);

        if (live) {
            const unsigned char* Kr = smem + cur * 16384 + wid * 4096;
            const bfrag kf0 = *(const bfrag*)(Kr + lo16);
            const bfrag kf1 = *(const bfrag*)(Kr + 1024 + lo16);
            const bfrag kf2 = *(const bfrag*)(Kr + 2048 + lo16);
            const bfrag kf3 = *(const bfrag*)(Kr + 3072 + lo16);

            const int kvb = j * 32 + gq * 4;
            #pragma unroll
            for (int sub = 0; sub < 2; ++sub) {
                f4 sh0 = {}, sh1 = {};       // S'[kv][q], swapped operands
                sh0 = __builtin_amdgcn_mfma_f32_16x16x32_bf16(kf0, qf[sub][0], sh0, 0, 0, 0);
                sh0 = __builtin_amdgcn_mfma_f32_16x16x32_bf16(kf1, qf[sub][1], sh0, 0, 0, 0);
                sh1 = __builtin_amdgcn_mfma_f32_16x16x32_bf16(kf2, qf[sub][0], sh1, 0, 0, 0);
                sh1 = __builtin_amdgcn_mfma_f32_16x16x32_bf16(kf3, qf[sub][1], sh1, 0, 0, 0);

                float p0[4], p1[4];
                if (j < qt) {                // interior tile: no masking at all
                    #pragma unroll
                    for (int e = 0; e < 4; ++e) {
                        p0[e] = fexp2(sh0[e]);
                        p1[e] = fexp2(sh1[e]);
                    }
                } else {                     // diagonal tile: per-element kv<=q
                    const int qg = qbase + sub * 16 + r;
                    #pragma unroll
                    for (int e = 0; e < 4; ++e) {
                        p0[e] = (kvb + e      <= qg) ? fexp2(sh0[e]) : 0.f;
                        p1[e] = (kvb + e + 16 <= qg) ? fexp2(sh1[e]) : 0.f;
                    }
                }

                PW pu;                       // sigma pack: slots 0-3 <- h0, 4-7 <- h1
                pu.w[0] = cvtpk(p0[0], p0[1]); pu.w[1] = cvtpk(p0[2], p0[3]);
                pu.w[2] = cvtpk(p1[0], p1[1]); pu.w[3] = cvtpk(p1[2], p1[3]);

                lsacc[sub] = __builtin_amdgcn_mfma_f32_16x16x32_bf16(pu.v, ones, lsacc[sub], 0, 0, 0);
                #pragma unroll
                for (int dt = 0; dt < 4; ++dt)
                    o[sub][dt] = __builtin_amdgcn_mfma_f32_16x16x32_bf16(pu.v, vf[dt], o[sub][dt], 0, 0, 0);
            }
        }

        __syncthreads();                     // reads done + K prefetch landed
        cur ^= 1;
    }

    // ---- epilogue: combine 4 waves' partials (reuse smem) ----
    float* Ol  = (float*)smem;               // [4][32][66] = 33792 B
    float* Lsm = (float*)(smem + 33792);     // [4][32]
    #pragma unroll
    for (int sub = 0; sub < 2; ++sub) {
        // lsacc: D[q=gq*4+e][col=r], all cols equal -> r==0 lanes hold it
        if (r == 0)
            #pragma unroll
            for (int e = 0; e < 4; ++e)
                Lsm[wid * 32 + sub * 16 + gq * 4 + e] = lsacc[sub][e];
        #pragma unroll
        for (int dt = 0; dt < 4; ++dt)
            #pragma unroll
            for (int e = 0; e < 4; ++e)
                Ol[(wid * 32 + sub * 16 + gq * 4 + e) * 66 + dt * 16 + r] = o[sub][dt][e];
    }
    __syncthreads();

    for (int i = tid; i < 32 * 64; i += 256) {
        const int row = i >> 6, col = i & 63;
        const float sum = Ol[(row) * 66 + col] + Ol[(32 + row) * 66 + col]
                        + Ol[(64 + row) * 66 + col] + Ol[(96 + row) * 66 + col];
        Opart[((long long)g4 * SEQ + qbase + row) * DM + col] = sum;
    }
    if (tid < 32) {
        const float l = Lsm[tid] + Lsm[32 + tid] + Lsm[64 + tid] + Lsm[96 + tid];
        Lpart[g4 * SEQ + qbase + tid] = l;
    }
}

// ---------------------------------------------------------------------------
// Kernel 3: out = (O0+O1+O2+O3) / (L0+L1+L2+L3)
// ---------------------------------------------------------------------------
__global__ __launch_bounds__(256) void normalize(
    const float* __restrict__ Opart, const float* __restrict__ Lpart,
    float* __restrict__ out)
{
    const int i = blockIdx.x * 256 + threadIdx.x;     // f4 index
    const f4* O = (const f4*)Opart;
    const int N = SEQ * DM / 4;
    const int row = i >> 4;
    const f4 a0 = O[i], a1 = O[N + i], a2 = O[2 * N + i], a3 = O[3 * N + i];
    const float l = (Lpart[row] + Lpart[SEQ + row])
                  + (Lpart[2 * SEQ + row] + Lpart[3 * SEQ + row]);
    const float inv = 1.0f / l;
    f4 res;
    #pragma unroll
    for (int e = 0; e < 4; ++e) res[e] = ((a0[e] + a1[e]) + (a2[e] + a3[e])) * inv;
    ((f4*)out)[i] = res;
}

extern "C" void kernel_launch(void* const* d_in, const int* in_sizes, int n_in,
                              void* d_out, int out_size, void* d_ws, size_t ws_size,
                              hipStream_t stream)
{
    (void)in_sizes; (void)n_in; (void)out_size; (void)ws_size;
    const float* x  = (const float*)d_in[0];
    const float* wq = (const float*)d_in[1];
    const float* bq = (const float*)d_in[2];
    const float* wk = (const float*)d_in[3];
    const float* bk = (const float*)d_in[4];
    const float* wv = (const float*)d_in[5];
    const float* bv = (const float*)d_in[6];
    float* out = (float*)d_out;

    __bf16* Qb = (__bf16*)d_ws;                       // [S][64] bf16, 1 MB
    __bf16* Ks = Qb + SEQ * DM;                       // tile-major K, 1 MB
    __bf16* Vg = Ks + SEQ * DM;                       // tile-major sigma V, 1 MB
    float*  Opart = (float*)(Vg + SEQ * DM);          // [4][S][64] f32, 8 MB
    float*  Lpart = Opart + 4 * SEQ * DM;             // [4][S] f32, 128 KB

    qkv_proj<<<1536, 256, 0, stream>>>(x, wq, bq, wk, bk, wv, bv, Qb, Ks, Vg);
    flash_attn<<<1024, 256, 0, stream>>>(Qb, Ks, Vg, Opart, Lpart);
    normalize<<<SEQ * DM / 4 / 256, 256, 0, stream>>>(Opart, Lpart, out);
}

// Round 14
// 34.235 us; speedup vs baseline: 1.4834x; 1.0447x over previous
//
#include <hip/hip_runtime.h>

#define SEQ 8192
#define DM 64

typedef __bf16 bfrag __attribute__((ext_vector_type(8)));   // MFMA A/B operand
typedef __bf16 b4v   __attribute__((ext_vector_type(4)));   // 8-byte bf16 pack
typedef float  f4    __attribute__((ext_vector_type(4)));   // MFMA C/D operand

union PW { int w[4]; bfrag v; };

// fold 1/sqrt(64) * log2(e) into Q so softmax is a bare v_exp_f32 (2^x)
#define QSCALE 0.1803368801111204f

__device__ inline float fexp2(float x) {        // guaranteed native v_exp_f32
    float y;
    asm("v_exp_f32 %0, %1" : "=v"(y) : "v"(x));
    return y;
}

__device__ inline int cvtpk(float a, float b) { // packed 2xbf16 in one instr
    int d;
    asm("v_cvt_pk_bf16_f32 %0, %1, %2" : "=v"(d) : "v"(a), "v"(b));
    return d;
}

// split f32 x8 into bf16 hi + bf16 lo (residual) for near-fp32 MFMA matmul
__device__ inline void split8(const float* __restrict__ p, bfrag& hi, bfrag& lo) {
    #pragma unroll
    for (int e = 0; e < 8; ++e) {
        const float v = p[e];
        const __bf16 h = (__bf16)v;
        hi[e] = h;
        lo[e] = (__bf16)(v - (float)h);
    }
}

// ---------------------------------------------------------------------------
// Kernel 1 (MFMA): 6144 wave-tasks = (m, 16-row x-tile rt, dt). 1536 blocks
// x 4 waves = 24 waves/CU. hi/lo split (~fp32 accuracy). Unchanged (r12/r13).
// ---------------------------------------------------------------------------
__global__ __launch_bounds__(256) void qkv_proj(
    const float* __restrict__ x,
    const float* __restrict__ wq, const float* __restrict__ bq,
    const float* __restrict__ wk, const float* __restrict__ bk,
    const float* __restrict__ wv, const float* __restrict__ bv,
    __bf16* __restrict__ Qb, __bf16* __restrict__ Ks, __bf16* __restrict__ Vg)
{
    const int lane = threadIdx.x & 63;
    const int wid  = threadIdx.x >> 6;
    const int task = blockIdx.x * 4 + wid;      // 0..6143
    const int m    = task >> 11;                // 0..2
    const int rest = task & 2047;
    const int rt   = rest >> 2;                 // 0..511
    const int dt   = rest & 3;                  // 0..3
    const int rb   = rt << 4;
    const int g = lane >> 4, r = lane & 15;

    const float* w = (m == 0) ? wq : (m == 1) ? wk : wv;

    bfrag xhi[2], xlo[2];
    #pragma unroll
    for (int kh = 0; kh < 2; ++kh)
        split8(x + (rb + r) * DM + kh * 32 + g * 8, xhi[kh], xlo[kh]);
    bfrag whi[2], wlo[2];
    #pragma unroll
    for (int kh = 0; kh < 2; ++kh)
        split8(w + (dt * 16 + r) * DM + kh * 32 + g * 8, whi[kh], wlo[kh]);

    if (m < 2) {                                // Q/K: mfma(W, X) -> D[feat][x-row]
        f4 acc = {0.f, 0.f, 0.f, 0.f};
        #pragma unroll
        for (int kh = 0; kh < 2; ++kh) {
            acc = __builtin_amdgcn_mfma_f32_16x16x32_bf16(whi[kh], xhi[kh], acc, 0, 0, 0);
            acc = __builtin_amdgcn_mfma_f32_16x16x32_bf16(wlo[kh], xhi[kh], acc, 0, 0, 0);
            acc = __builtin_amdgcn_mfma_f32_16x16x32_bf16(whi[kh], xlo[kh], acc, 0, 0, 0);
        }
        const float* bias = (m == 0) ? bq : bk;
        const int c0 = dt * 16 + g * 4;         // 4 consecutive features
        const float4 b4 = *(const float4*)(bias + c0);
        const float sc = (m == 0) ? QSCALE : 1.0f;
        b4v pv;
        pv[0] = (__bf16)((acc[0] + b4.x) * sc);
        pv[1] = (__bf16)((acc[1] + b4.y) * sc);
        pv[2] = (__bf16)((acc[2] + b4.z) * sc);
        pv[3] = (__bf16)((acc[3] + b4.w) * sc);
        if (m == 0) {
            *(b4v*)(Qb + (rb + r) * DM + c0) = pv;
        } else {
            const int row = rb + r, t = row >> 5, row32 = row & 31;
            const int ch  = dt * 2 + (g >> 1);
            const int b2  = ((row32 >> 4) << 1) | (ch >> 2);
            *(b4v*)(Ks + t * 2048 + b2 * 512 + (ch & 3) * 128
                       + (row32 & 15) * 8 + (g & 1) * 4) = pv;
        }
    } else {                                    // V: mfma(X, W) -> D[x-row(kv)][feat]
        f4 acc = {0.f, 0.f, 0.f, 0.f};
        #pragma unroll
        for (int kh = 0; kh < 2; ++kh) {
            acc = __builtin_amdgcn_mfma_f32_16x16x32_bf16(xhi[kh], whi[kh], acc, 0, 0, 0);
            acc = __builtin_amdgcn_mfma_f32_16x16x32_bf16(xlo[kh], whi[kh], acc, 0, 0, 0);
            acc = __builtin_amdgcn_mfma_f32_16x16x32_bf16(xhi[kh], wlo[kh], acc, 0, 0, 0);
        }
        const int d  = dt * 16 + r;
        const float bd = bv[d];
        const int L0 = (rb & 31) + g * 4;       // kv rows rb + g*4 + e
        const int P0 = ((L0 & 15) >> 2) * 8 + (L0 >> 4) * 4;  // sigma slot base
        const int t  = rb >> 5;
        b4v pv;
        pv[0] = (__bf16)(acc[0] + bd);
        pv[1] = (__bf16)(acc[1] + bd);
        pv[2] = (__bf16)(acc[2] + bd);
        pv[3] = (__bf16)(acc[3] + bd);
        *(b4v*)(Vg + t * 2048 + (d >> 4) * 512 + (P0 >> 3) * 128
                   + (d & 15) * 8 + (P0 & 7)) = pv;
    }
}

// ---------------------------------------------------------------------------
// Kernel 2: flash attention partials — BARRIER-FREE main loop.
// Grid 1024 = fam(0..255 -> qt, balanced) x g4(0..3). 4 waves/block.
// Each wave owns tiles j = 4*g4 + wid + 16*s, j <= qt: exact live list,
// zero wasted iterations, no live-guard, NO __syncthreads in the loop.
// K and V both read DIRECT from global (tile-major layouts: uniform +
// lane*16, 1KB/load coalesced, K+V = 2MB -> L2-resident per XCD). All 8
// loads are consumed in-iteration (nothing for the scheduler to sink);
// 4 independent waves/SIMD cover the L2 latency via TLP.
// Swapped QK^T + sigma PV + ones-MFMA row-sum + cvt_pk (verified r13).
// LDS used ONLY in the epilogue combine (single barrier).
// ---------------------------------------------------------------------------
__global__ __launch_bounds__(256)
__attribute__((amdgpu_waves_per_eu(4)))
void flash_attn(
    const __bf16* __restrict__ Qb, const __bf16* __restrict__ Ks,
    const __bf16* __restrict__ Vg,
    float* __restrict__ Opart, float* __restrict__ Lpart)
{
    __shared__ __align__(16) unsigned char smem[34816];  // epilogue only

    const int tid  = threadIdx.x;
    const int lane = tid & 63;
    const int wid  = tid >> 6;               // 0..3
    const int b    = blockIdx.x;
    const int fam  = b >> 2;                 // 0..255
    const int g4   = b & 3;                  // kv slice
    const int grp  = fam >> 6, hh = fam & 63;
    const int qt   = (grp == 0) ? (255 - hh) : (grp == 1) ? hh
                   : (grp == 2) ? (191 - hh) : (64 + hh);   // 4-way balanced
    const int qbase = qt * 32;
    const int gq = lane >> 4;                // 0..3
    const int r  = lane & 15;
    const int lo16 = lane << 4;

    bfrag qf[2][2];
    #pragma unroll
    for (int sub = 0; sub < 2; ++sub)
        #pragma unroll
        for (int kh = 0; kh < 2; ++kh)
            qf[sub][kh] = *(const bfrag*)(Qb + (qbase + sub * 16 + r) * DM + kh * 32 + gq * 8);

    bfrag ones;                              // B-operand of the row-sum MFMA
    #pragma unroll
    for (int e = 0; e < 8; ++e) ones[e] = (__bf16)1.0f;

    f4 o[2][4] = {};
    f4 lsacc[2] = {};                        // row-sums via MFMA (all cols equal)

    const char* Kbb = (const char*)Ks;
    const char* Vbb = (const char*)Vg;

    const int jw = g4 * 4 + wid;             // this wave's first tile
    const int nlive = (qt >= jw) ? ((qt - jw) >> 4) + 1 : 0;

    for (int s = 0; s < nlive; ++s) {
        const int j = jw + s * 16;           // uniform per wave, always live
        const long long jb = (long long)j * 4096;
        // direct K + V loads (8 x 1KB coalesced, L2-resident)
        const bfrag kf0 = *(const bfrag*)(Kbb + jb + lo16);
        const bfrag kf1 = *(const bfrag*)(Kbb + jb + 1024 + lo16);
        const bfrag kf2 = *(const bfrag*)(Kbb + jb + 2048 + lo16);
        const bfrag kf3 = *(const bfrag*)(Kbb + jb + 3072 + lo16);
        bfrag vf[4];
        #pragma unroll
        for (int dt = 0; dt < 4; ++dt)
            vf[dt] = *(const bfrag*)(Vbb + jb + dt * 1024 + lo16);

        const int kvb = j * 32 + gq * 4;
        #pragma unroll
        for (int sub = 0; sub < 2; ++sub) {
            f4 sh0 = {}, sh1 = {};           // S'[kv][q], swapped operands
            sh0 = __builtin_amdgcn_mfma_f32_16x16x32_bf16(kf0, qf[sub][0], sh0, 0, 0, 0);
            sh0 = __builtin_amdgcn_mfma_f32_16x16x32_bf16(kf1, qf[sub][1], sh0, 0, 0, 0);
            sh1 = __builtin_amdgcn_mfma_f32_16x16x32_bf16(kf2, qf[sub][0], sh1, 0, 0, 0);
            sh1 = __builtin_amdgcn_mfma_f32_16x16x32_bf16(kf3, qf[sub][1], sh1, 0, 0, 0);

            float p0[4], p1[4];
            if (j < qt) {                    // interior tile: bare exp
                #pragma unroll
                for (int e = 0; e < 4; ++e) {
                    p0[e] = fexp2(sh0[e]);
                    p1[e] = fexp2(sh1[e]);
                }
            } else {                         // diagonal tile: per-element kv<=q
                const int qg = qbase + sub * 16 + r;
                #pragma unroll
                for (int e = 0; e < 4; ++e) {
                    p0[e] = (kvb + e      <= qg) ? fexp2(sh0[e]) : 0.f;
                    p1[e] = (kvb + e + 16 <= qg) ? fexp2(sh1[e]) : 0.f;
                }
            }

            PW pu;                           // sigma pack: slots 0-3 <- h0, 4-7 <- h1
            pu.w[0] = cvtpk(p0[0], p0[1]); pu.w[1] = cvtpk(p0[2], p0[3]);
            pu.w[2] = cvtpk(p1[0], p1[1]); pu.w[3] = cvtpk(p1[2], p1[3]);

            lsacc[sub] = __builtin_amdgcn_mfma_f32_16x16x32_bf16(pu.v, ones, lsacc[sub], 0, 0, 0);
            #pragma unroll
            for (int dt = 0; dt < 4; ++dt)
                o[sub][dt] = __builtin_amdgcn_mfma_f32_16x16x32_bf16(pu.v, vf[dt], o[sub][dt], 0, 0, 0);
        }
    }

    // ---- epilogue: combine 4 waves' partials (single barrier) ----
    float* Ol  = (float*)smem;               // [4][32][66] = 33792 B
    float* Lsm = (float*)(smem + 33792);     // [4][32]
    #pragma unroll
    for (int sub = 0; sub < 2; ++sub) {
        // lsacc: D[q=gq*4+e][col=r], all cols equal -> r==0 lanes hold it
        if (r == 0)
            #pragma unroll
            for (int e = 0; e < 4; ++e)
                Lsm[wid * 32 + sub * 16 + gq * 4 + e] = lsacc[sub][e];
        #pragma unroll
        for (int dt = 0; dt < 4; ++dt)
            #pragma unroll
            for (int e = 0; e < 4; ++e)
                Ol[(wid * 32 + sub * 16 + gq * 4 + e) * 66 + dt * 16 + r] = o[sub][dt][e];
    }
    __syncthreads();

    for (int i = tid; i < 32 * 64; i += 256) {
        const int row = i >> 6, col = i & 63;
        const float sum = Ol[(row) * 66 + col] + Ol[(32 + row) * 66 + col]
                        + Ol[(64 + row) * 66 + col] + Ol[(96 + row) * 66 + col];
        Opart[((long long)g4 * SEQ + qbase + row) * DM + col] = sum;
    }
    if (tid < 32) {
        const float l = Lsm[tid] + Lsm[32 + tid] + Lsm[64 + tid] + Lsm[96 + tid];
        Lpart[g4 * SEQ + qbase + tid] = l;
    }
}

// ---------------------------------------------------------------------------
// Kernel 3: out = (O0+O1+O2+O3) / (L0+L1+L2+L3)
// ---------------------------------------------------------------------------
__global__ __launch_bounds__(256) void normalize(
    const float* __restrict__ Opart, const float* __restrict__ Lpart,
    float* __restrict__ out)
{
    const int i = blockIdx.x * 256 + threadIdx.x;     // f4 index
    const f4* O = (const f4*)Opart;
    const int N = SEQ * DM / 4;
    const int row = i >> 4;
    const f4 a0 = O[i], a1 = O[N + i], a2 = O[2 * N + i], a3 = O[3 * N + i];
    const float l = (Lpart[row] + Lpart[SEQ + row])
                  + (Lpart[2 * SEQ + row] + Lpart[3 * SEQ + row]);
    const float inv = 1.0f / l;
    f4 res;
    #pragma unroll
    for (int e = 0; e < 4; ++e) res[e] = ((a0[e] + a1[e]) + (a2[e] + a3[e])) * inv;
    ((f4*)out)[i] = res;
}

extern "C" void kernel_launch(void* const* d_in, const int* in_sizes, int n_in,
                              void* d_out, int out_size, void* d_ws, size_t ws_size,
                              hipStream_t stream)
{
    (void)in_sizes; (void)n_in; (void)out_size; (void)ws_size;
    const float* x  = (const float*)d_in[0];
    const float* wq = (const float*)d_in[1];
    const float* bq = (const float*)d_in[2];
    const float* wk = (const float*)d_in[3];
    const float* bk = (const float*)d_in[4];
    const float* wv = (const float*)d_in[5];
    const float* bv = (const float*)d_in[6];
    float* out = (float*)d_out;

    __bf16* Qb = (__bf16*)d_ws;                       // [S][64] bf16, 1 MB
    __bf16* Ks = Qb + SEQ * DM;                       // tile-major K, 1 MB
    __bf16* Vg = Ks + SEQ * DM;                       // tile-major sigma V, 1 MB
    float*  Opart = (float*)(Vg + SEQ * DM);          // [4][S][64] f32, 8 MB
    float*  Lpart = Opart + 4 * SEQ * DM;             // [4][S] f32, 128 KB

    qkv_proj<<<1536, 256, 0, stream>>>(x, wq, bq, wk, bk, wv, bv, Qb, Ks, Vg);
    flash_attn<<<1024, 256, 0, stream>>>(Qb, Ks, Vg, Opart, Lpart);
    normalize<<<SEQ * DM / 4 / 256, 256, 0, stream>>>(Opart, Lpart, out);
}